// Round 8
// baseline (750.556 us; speedup 1.0000x reference)
//
#include <hip/hip_runtime.h>

// ---------------------------------------------------------------------------
// Triplane sample + 4-layer MLP, N=1e6 points. 2 dispatches:
//   D1 prep_kernel: [blocks 0..3071] transpose planes f32->f16 (x256, chan-
//       contiguous); [3072..3215] weights f32->f16.
//   D2 fused_kernel: sample 64 pts/block (original order) -> LDS feats ->
//       pair-split MFMA MLP -> out[p] (coalesced).
// Scale S=256 keeps f16 in normal range; epilogues add S*b in fp32; final
// layer divides by S in fp32.
//
// R1 (FAILED, 294us): 32-pt waves -> ILP collapse + 2x W traffic.
// R2 (NEUTRAL): pair-split 4 blk/CU; by-ref acc spilled (WRITE 70MB).
// R3 (NEUTRAL, 177us): de-spilled; mlp latency-chain bound, not occupancy.
// R4 (WIN, 598->509us): fused sample+MLP (238us vs 327us for the pair).
// R5/R6 (FAILED, ~800us): coop sort intrinsically stall-bound. Abandoned.
// R7 (WIN, 446us): dropped Morton sort; unsorted fused = 287us, FETCH 577MB
//   (~no-reuse floor), gather-miss stall dominated; occupancy 44% (LDS cap
//   4 blk/CU). Overhead model: fixed ~90us + ~10us/dispatch -> sorted
//   variants can't win. Lever: miss-level parallelism via occupancy.
// R8: 1 pair per 128-thread block + HPAD 136->128 with 16B-chunk XOR swizzle
//   (chunk ^= row&15) instead of pad. LDS/block 16384B -> 10 blocks/CU =
//   20 waves/CU (was 16). Swizzled reads 2-way bank (free); phase-2 logic
//   otherwise identical. Grid 15625 (1M/64, no tail).
// ---------------------------------------------------------------------------

#define SF 256.0f
#define FSTR 40   // halves per point-row for LDS feats overlay (32 + 8 pad)

typedef _Float16 half8 __attribute__((ext_vector_type(8)));
typedef _Float16 half4_t __attribute__((ext_vector_type(4)));
typedef float f32x4 __attribute__((ext_vector_type(4)));
typedef unsigned int u32x4 __attribute__((ext_vector_type(4)));

// ---------------- D1: prep (plane transpose + weights convert) -------------
__global__ __launch_bounds__(256) void prep_kernel(
    const float* __restrict__ planes, _Float16* __restrict__ ph,
    const float* __restrict__ w0, const float* __restrict__ w1,
    const float* __restrict__ w2, _Float16* __restrict__ w0h,
    _Float16* __restrict__ w1h, _Float16* __restrict__ w2h) {
  int bid = blockIdx.x;
  if (bid < 3072) {
    // plane transpose+convert+scale: 3*2^18 threads exactly
    int t = bid * 256 + threadIdx.x;
    int pid = t >> 18;
    int rem = t & ((1 << 18) - 1);              // y*512 + x
    const float* src = planes + ((size_t)pid << 23) + rem;  // [pid][c][y][x]
    union { _Float16 h[32]; u32x4 v[4]; } u;
#pragma unroll
    for (int c = 0; c < 32; c++)
      u.h[c] = (_Float16)(src[(size_t)c << 18] * SF);
    u32x4* dst = reinterpret_cast<u32x4*>(ph + ((size_t)t << 5));
#pragma unroll
    for (int i = 0; i < 4; i++) dst[i] = u.v[i];
  } else {
    // weights f32 -> f16: 36864 threads exactly (144 blocks)
    int t = (bid - 3072) * 256 + threadIdx.x;
    if (t < 4096) w0h[t] = (_Float16)w0[t];
    else if (t < 20480) w1h[t - 4096] = (_Float16)w1[t - 4096];
    else w2h[t - 20480] = (_Float16)w2[t - 20480];
  }
}

// ---------------- bilinear sampling: 16 channels (hf selects half) --------
__device__ __attribute__((always_inline)) inline void samp16(
    const _Float16* __restrict__ pl, float X, float Y, int hf, float* acc) {
  float fx = (X + 1.0f) * 0.5f * 511.0f;
  float fy = (Y + 1.0f) * 0.5f * 511.0f;
  float x0f = floorf(fx), y0f = floorf(fy);
  float wx1 = fx - x0f, wy1 = fy - y0f;
  float wx0 = 1.0f - wx1, wy0 = 1.0f - wy1;
  int x0 = (int)x0f, y0 = (int)y0f;
  int x1 = x0 + 1, y1 = y0 + 1;
  float vx0 = (x0 >= 0 && x0 < 512) ? 1.0f : 0.0f;
  float vx1 = (x1 >= 0 && x1 < 512) ? 1.0f : 0.0f;
  float vy0 = (y0 >= 0 && y0 < 512) ? 1.0f : 0.0f;
  float vy1 = (y1 >= 0 && y1 < 512) ? 1.0f : 0.0f;
  int xc0 = min(max(x0, 0), 511), xc1 = min(max(x1, 0), 511);
  int yc0 = min(max(y0, 0), 511), yc1 = min(max(y1, 0), 511);
  float w00 = wx0 * wy0 * vx0 * vy0, w10 = wx1 * wy0 * vx1 * vy0;
  float w01 = wx0 * wy1 * vx0 * vy1, w11 = wx1 * wy1 * vx1 * vy1;
  const _Float16* p00 = pl + ((((size_t)yc0 << 9) + xc0) << 5) + hf * 16;
  const _Float16* p10 = pl + ((((size_t)yc0 << 9) + xc1) << 5) + hf * 16;
  const _Float16* p01 = pl + ((((size_t)yc1 << 9) + xc0) << 5) + hf * 16;
  const _Float16* p11 = pl + ((((size_t)yc1 << 9) + xc1) << 5) + hf * 16;
#pragma unroll
  for (int ch = 0; ch < 2; ch++) {
    union { u32x4 v; _Float16 h[8]; } a, b, c, d;
    a.v = *reinterpret_cast<const u32x4*>(p00 + ch * 8);
    b.v = *reinterpret_cast<const u32x4*>(p10 + ch * 8);
    c.v = *reinterpret_cast<const u32x4*>(p01 + ch * 8);
    d.v = *reinterpret_cast<const u32x4*>(p11 + ch * 8);
#pragma unroll
    for (int j = 0; j < 8; j++) {
      acc[ch * 8 + j] += w00 * (float)a.h[j] + w10 * (float)b.h[j] +
                         w01 * (float)c.h[j] + w11 * (float)d.h[j];
    }
  }
}

// ---------------- D2: fused sample + MLP ----------------
// Block = 128 threads = 1 pair = 64 points; LDS 16384 B -> 10 blocks/CU
// (20 waves/CU). H is [row][128 halves] with 16B-chunk XOR swizzle
// (chunk ^= row&15) -- replaces the old +8 pad; LAYER reads land 2-way
// bank (free). Phase 1: 2 threads/pt sample 16ch each -> LDS feats
// (FSTR stride, overlaid at front of H region, unswizzled). Phase 2:
// pair-split MLP -- wave w owns hidden rows 64w..64w+63; MACRO body,
// per-mt fused epilogue (no spill; VGPR ~64 < 102 cap at (128,5)).
__device__ __attribute__((always_inline)) inline half8 ld16(const _Float16* p) {
  return *reinterpret_cast<const half8*>(p);
}

// half-index of the 16B chunk (8 halves) `c` in swizzled row `r`
__device__ __attribute__((always_inline)) inline int hswz(int r, int c) {
  return r * 128 + ((c ^ (r & 15)) << 3);
}

#define LAYER_PAIR(Wg, bias)                                                   \
  {                                                                            \
    half8 Bf[4][4]; /* [nt][ks] : 64 regs */                                   \
    _Pragma("unroll") for (int nt = 0; nt < 4; nt++)                           \
    _Pragma("unroll") for (int ks = 0; ks < 4; ks++)                           \
        Bf[nt][ks] = ld16(&H[hswz(nt * 16 + n16, 4 * ks + g)]);                \
    __syncthreads(); /* all H reads done; safe to overwrite */                 \
    _Pragma("unroll") for (int mt = 0; mt < 4; mt++) {                         \
      f32x4 acc[4];                                                            \
      _Pragma("unroll") for (int nt = 0; nt < 4; nt++) acc[nt] = Z4;           \
      _Pragma("unroll") for (int ks = 0; ks < 4; ks++) {                       \
        half8 A = ld16((Wg) + ((w * 4 + mt) * 16 + n16) * 128 + ks * 32 + g * 8); \
        _Pragma("unroll") for (int nt = 0; nt < 4; nt++)                       \
            acc[nt] = __builtin_amdgcn_mfma_f32_16x16x32_f16(A, Bf[nt][ks],    \
                                                             acc[nt], 0, 0, 0); \
      }                                                                        \
      int gm = w * 4 + mt;                                                     \
      f32x4 bb = *reinterpret_cast<const f32x4*>((bias) + gm * 16 + g * 4);    \
      _Pragma("unroll") for (int nt = 0; nt < 4; nt++) {                       \
        half4_t v;                                                             \
        _Pragma("unroll") for (int r = 0; r < 4; r++)                          \
            v[r] = (_Float16)fmaxf(acc[nt][r] + SF * bb[r], 0.0f);             \
        *reinterpret_cast<half4_t*>(                                           \
            &H[hswz(nt * 16 + n16, 2 * gm + (g >> 1)) + (g & 1) * 4]) = v;     \
      }                                                                        \
    }                                                                          \
    __syncthreads(); /* H writes visible to partner */                         \
  }

__global__ __launch_bounds__(128, 5) void fused_kernel(
    const float* __restrict__ coords, const _Float16* __restrict__ ph,
    const _Float16* __restrict__ w0h, const _Float16* __restrict__ w1h,
    const _Float16* __restrict__ w2h, const float* __restrict__ b0,
    const float* __restrict__ b1, const float* __restrict__ b2,
    const float* __restrict__ w3, const float* __restrict__ b3,
    float* __restrict__ out, int npts) {
  __shared__ alignas(16) _Float16 hbuf[64 * 128];  // 16384 B -> 10 blk/CU
  int tid = threadIdx.x;
  int sb = blockIdx.x;  // natural order: coalesced coords reads + out writes

  // ---- phase 1: sample 64 points; 2 threads/pt, 16 channels each ----
  {
    int ptl = tid >> 1, hf = tid & 1;  // ptl 0..63
    long pb = (long)sb * 64;
    if (pb + 64 > npts) pb = npts - 64;  // tail: duplicate identical work
    long pp = pb + ptl;
    float cx = coords[3 * pp + 0];
    float cy = coords[3 * pp + 1];
    float cz = coords[3 * pp + 2];
    float acc[16];
#pragma unroll
    for (int c = 0; c < 16; c++) acc[c] = 0.0f;
    samp16(ph, cx, cy, hf, acc);                  // plane 0: (x, y)
    samp16(ph + (1u << 23), cy, cz, hf, acc);     // plane 1: (y, z)
    samp16(ph + (2u << 23), cx, cz, hf, acc);     // plane 2: (x, z)
    union { _Float16 h[16]; u32x4 v[2]; } u;
#pragma unroll
    for (int c = 0; c < 16; c++) u.h[c] = (_Float16)acc[c];
    // feats row stride FSTR=40 halves (80B), unswizzled; max idx 2551 < 8192
    *reinterpret_cast<u32x4*>(&hbuf[ptl * FSTR + hf * 16]) = u.v[0];
    *reinterpret_cast<u32x4*>(&hbuf[ptl * FSTR + hf * 16 + 8]) = u.v[1];
  }
  __syncthreads();  // feats visible to both waves

  // ---- phase 2: pair-split MLP (pair = the block's 2 waves) ----
  int wv = tid >> 6, lane = tid & 63;
  int w = wv;  // wave w owns hidden rows 64w..64w+63
  int n16 = lane & 15, g = lane >> 4;
  long base = (long)sb * 64;
  if (base + 64 > npts) base = npts - 64;  // same clamp as phase 1
  _Float16* H = hbuf;
  const f32x4 Z4 = {0.0f, 0.0f, 0.0f, 0.0f};

  // layer 0: C^T = W0(rows 64w..64w+63, x32) * feats^T(32x64); K=32.
  {
    half8 Bf[4];
#pragma unroll
    for (int nt = 0; nt < 4; nt++)
      Bf[nt] = ld16(&H[(nt * 16 + n16) * FSTR + g * 8]);  // LDS feats
    __syncthreads();  // feats reads done; epilogue may overwrite region
#pragma unroll
    for (int mt = 0; mt < 4; mt++) {
      half8 A = ld16(w0h + ((w * 4 + mt) * 16 + n16) * 32 + g * 8);
      f32x4 acc[4];
#pragma unroll
      for (int nt = 0; nt < 4; nt++)
        acc[nt] = __builtin_amdgcn_mfma_f32_16x16x32_f16(A, Bf[nt], Z4, 0, 0, 0);
      int gm = w * 4 + mt;
      f32x4 bb = *reinterpret_cast<const f32x4*>(b0 + gm * 16 + g * 4);
#pragma unroll
      for (int nt = 0; nt < 4; nt++) {
        half4_t v;
#pragma unroll
        for (int r = 0; r < 4; r++)
          v[r] = (_Float16)fmaxf(acc[nt][r] + SF * bb[r], 0.0f);
        *reinterpret_cast<half4_t*>(
            &H[hswz(nt * 16 + n16, 2 * gm + (g >> 1)) + (g & 1) * 4]) = v;
      }
    }
    __syncthreads();  // H(L0) visible before L1 reads
  }

  LAYER_PAIR(w1h, b1)
  LAYER_PAIR(w2h, b2)

  // layer 3: out = dot(h2, w3)/S + b3, fp32 VALU.
  // Pair covers 64 pts; wave w takes pts w*32..+31. lane = pt' + 32*half;
  // each half does 8 of 16 chunks, reduce across halves via shfl_xor(32).
  int ptl3 = lane & 31, hh = lane >> 5;
  int pt = w * 32 + ptl3;
  float o = 0.0f;
#pragma unroll
  for (int ii = 0; ii < 8; ii++) {
    int i = hh * 8 + ii;
    half8 hv = ld16(&H[hswz(pt, i)]);
#pragma unroll
    for (int j = 0; j < 8; j++) o += (float)hv[j] * w3[i * 8 + j];
  }
  o += __shfl_xor(o, 32);
  if (lane < 32) {
    out[base + pt] = o * (1.0f / SF) + b3[0];  // coalesced
  }
}

// ---------------- launch ----------------
extern "C" void kernel_launch(void* const* d_in, const int* in_sizes, int n_in,
                              void* d_out, int out_size, void* d_ws, size_t ws_size,
                              hipStream_t stream) {
  const float* coords = (const float*)d_in[0];
  const float* planes = (const float*)d_in[1];
  const float* w0 = (const float*)d_in[2];
  const float* b0 = (const float*)d_in[3];
  const float* w1 = (const float*)d_in[4];
  const float* b1 = (const float*)d_in[5];
  const float* w2 = (const float*)d_in[6];
  const float* b2 = (const float*)d_in[7];
  const float* w3 = (const float*)d_in[8];
  const float* b3 = (const float*)d_in[9];
  float* out = (float*)d_out;
  int npts = in_sizes[0] / 3;  // 1,000,000

  // workspace layout (bytes):
  //   ph       @ 0          50,331,648
  //   w0h      @ 50331648   8,192
  //   w1h      @ 50339840   32,768
  //   w2h      @ 50372608   32,768
  char* ws = (char*)d_ws;
  _Float16* ph = (_Float16*)ws;
  _Float16* w0h = (_Float16*)(ws + 50331648);
  _Float16* w1h = (_Float16*)(ws + 50339840);
  _Float16* w2h = (_Float16*)(ws + 50372608);

  int fblk = (npts + 63) / 64;  // 64 pts per block (1 pair) = 15625

  // D1: transpose (3072) + weights (144) = 3216 blocks
  prep_kernel<<<3216, 256, 0, stream>>>(planes, ph, w0, w1, w2, w0h, w1h, w2h);
  // D2: fused sample + MLP, original point order
  fused_kernel<<<fblk, 128, 0, stream>>>(coords, ph, w0h, w1h, w2h, b0, b1, b2,
                                         w3, b3, out, npts);
}

// Round 9
// 414.978 us; speedup vs baseline: 1.8087x; 1.8087x over previous
//
#include <hip/hip_runtime.h>

// ---------------------------------------------------------------------------
// Triplane sample + 4-layer MLP, N=1e6 points. 2 dispatches:
//   D1 prep_kernel: [blocks 0..3071] transpose planes f32->f16 (x256, chan-
//       contiguous); [3072..3215] weights f32->f16.
//   D2 fused_kernel: sample 128 pts/block (original order) -> LDS feats ->
//       pair-split MFMA MLP -> out[p] (coalesced).
// Scale S=256 keeps f16 in normal range; epilogues add S*b in fp32; final
// layer divides by S in fp32.
//
// R1 (FAILED, 294us): 32-pt waves -> ILP collapse + 2x W traffic.
// R2 (NEUTRAL): pair-split 4 blk/CU; by-ref acc spilled (WRITE 70MB).
// R3 (NEUTRAL, 177us): de-spilled mlp; latency-chain bound.
// R4 (WIN, 598->509us): fused sample+MLP.
// R5/R6 (FAILED, ~800us): coop sort intrinsically stall-bound. Abandoned.
// R7 (WIN, 446us): dropped Morton sort; fused 287us, FETCH 577MB, occ 44%.
// R8 (FAILED, 750us): (128,5) bound capped VGPR ~102 < ~105 live -> huge
//   spill (VGPR=48, 1.36GB fetch / 1.15GB write). Geometry reverted.
//   KEY FIND: R4/R7 fused was spilling all along -- WRITE 113MB >> 4MB out,
//   VGPR=64: the type-punning UNIONS in samp16/phase-1 are lowered via
//   scratch slots (~55B/thread). R3's clean kernel had no hot-path unions.
// R9: de-union. All texel loads/stores use half8 ext-vectors directly
//   ((float)v[j] extracts are register ops, indices static). Geometry,
//   barriers, layer code identical to R7.
// ---------------------------------------------------------------------------

#define SF 256.0f
#define HPAD 136  // halves per point-row in LDS H (128 + 8 pad), 16B aligned
#define FSTR 40   // halves per point-row for LDS feats overlay (32 + 8 pad)

typedef _Float16 half8 __attribute__((ext_vector_type(8)));
typedef _Float16 half4_t __attribute__((ext_vector_type(4)));
typedef float f32x4 __attribute__((ext_vector_type(4)));

__device__ __attribute__((always_inline)) inline half8 ld16(const _Float16* p) {
  return *reinterpret_cast<const half8*>(p);
}
__device__ __attribute__((always_inline)) inline void st16(_Float16* p, half8 v) {
  *reinterpret_cast<half8*>(p) = v;
}

// ---------------- D1: prep (plane transpose + weights convert) -------------
__global__ __launch_bounds__(256) void prep_kernel(
    const float* __restrict__ planes, _Float16* __restrict__ ph,
    const float* __restrict__ w0, const float* __restrict__ w1,
    const float* __restrict__ w2, _Float16* __restrict__ w0h,
    _Float16* __restrict__ w1h, _Float16* __restrict__ w2h) {
  int bid = blockIdx.x;
  if (bid < 3072) {
    // plane transpose+convert+scale: 3*2^18 threads exactly
    int t = bid * 256 + threadIdx.x;
    int pid = t >> 18;
    int rem = t & ((1 << 18) - 1);              // y*512 + x
    const float* src = planes + ((size_t)pid << 23) + rem;  // [pid][c][y][x]
    half8 o[4];  // statically indexed after unroll -> registers
#pragma unroll
    for (int c = 0; c < 32; c++)
      o[c >> 3][c & 7] = (_Float16)(src[(size_t)c << 18] * SF);
    _Float16* dst = ph + ((size_t)t << 5);
#pragma unroll
    for (int i = 0; i < 4; i++) st16(dst + i * 8, o[i]);
  } else {
    // weights f32 -> f16: 36864 threads exactly (144 blocks)
    int t = (bid - 3072) * 256 + threadIdx.x;
    if (t < 4096) w0h[t] = (_Float16)w0[t];
    else if (t < 20480) w1h[t - 4096] = (_Float16)w1[t - 4096];
    else w2h[t - 20480] = (_Float16)w2[t - 20480];
  }
}

// ---------------- bilinear sampling: 16 channels (hf selects half) --------
// De-unioned: half8 vector loads + per-element (float) extracts (reg ops).
__device__ __attribute__((always_inline)) inline void samp16(
    const _Float16* __restrict__ pl, float X, float Y, int hf, float* acc) {
  float fx = (X + 1.0f) * 0.5f * 511.0f;
  float fy = (Y + 1.0f) * 0.5f * 511.0f;
  float x0f = floorf(fx), y0f = floorf(fy);
  float wx1 = fx - x0f, wy1 = fy - y0f;
  float wx0 = 1.0f - wx1, wy0 = 1.0f - wy1;
  int x0 = (int)x0f, y0 = (int)y0f;
  int x1 = x0 + 1, y1 = y0 + 1;
  float vx0 = (x0 >= 0 && x0 < 512) ? 1.0f : 0.0f;
  float vx1 = (x1 >= 0 && x1 < 512) ? 1.0f : 0.0f;
  float vy0 = (y0 >= 0 && y0 < 512) ? 1.0f : 0.0f;
  float vy1 = (y1 >= 0 && y1 < 512) ? 1.0f : 0.0f;
  int xc0 = min(max(x0, 0), 511), xc1 = min(max(x1, 0), 511);
  int yc0 = min(max(y0, 0), 511), yc1 = min(max(y1, 0), 511);
  float w00 = wx0 * wy0 * vx0 * vy0, w10 = wx1 * wy0 * vx1 * vy0;
  float w01 = wx0 * wy1 * vx0 * vy1, w11 = wx1 * wy1 * vx1 * vy1;
  const _Float16* p00 = pl + ((((size_t)yc0 << 9) + xc0) << 5) + hf * 16;
  const _Float16* p10 = pl + ((((size_t)yc0 << 9) + xc1) << 5) + hf * 16;
  const _Float16* p01 = pl + ((((size_t)yc1 << 9) + xc0) << 5) + hf * 16;
  const _Float16* p11 = pl + ((((size_t)yc1 << 9) + xc1) << 5) + hf * 16;
#pragma unroll
  for (int ch = 0; ch < 2; ch++) {
    half8 a = ld16(p00 + ch * 8);
    half8 b = ld16(p10 + ch * 8);
    half8 c = ld16(p01 + ch * 8);
    half8 d = ld16(p11 + ch * 8);
#pragma unroll
    for (int j = 0; j < 8; j++) {
      acc[ch * 8 + j] += w00 * (float)a[j] + w10 * (float)b[j] +
                         w01 * (float)c[j] + w11 * (float)d[j];
    }
  }
}

// ---------------- D2: fused sample + MLP ----------------
// Block = 256 threads = 2 pairs = 128 points; LDS 34816 B -> 4 blocks/CU.
// Phase 1: 2 threads/pt sample 16ch each -> LDS feats (stride FSTR halves).
// Phase 2: pair-split MLP -- 2 waves share one 64-pt H buffer; wave w owns
//   hidden rows 64w..64w+63. Layer body is a MACRO (no call boundary), B
//   preloaded, per-mt fused epilogue: no spill, peak ~105 VGPR < 128 cap.
#define LAYER_PAIR(Wg, bias)                                                   \
  {                                                                            \
    half8 Bf[4][4]; /* [nt][ks] : 64 regs */                                   \
    _Pragma("unroll") for (int nt = 0; nt < 4; nt++)                           \
    _Pragma("unroll") for (int ks = 0; ks < 4; ks++)                           \
        Bf[nt][ks] = ld16(&H[(nt * 16 + n16) * HPAD + ks * 32 + g * 8]);       \
    __syncthreads(); /* all H reads done; safe to overwrite */                 \
    _Pragma("unroll") for (int mt = 0; mt < 4; mt++) {                         \
      f32x4 acc[4];                                                            \
      _Pragma("unroll") for (int nt = 0; nt < 4; nt++) acc[nt] = Z4;           \
      _Pragma("unroll") for (int ks = 0; ks < 4; ks++) {                       \
        half8 A = ld16((Wg) + ((w * 4 + mt) * 16 + n16) * 128 + ks * 32 + g * 8); \
        _Pragma("unroll") for (int nt = 0; nt < 4; nt++)                       \
            acc[nt] = __builtin_amdgcn_mfma_f32_16x16x32_f16(A, Bf[nt][ks],    \
                                                             acc[nt], 0, 0, 0); \
      }                                                                        \
      int gm = w * 4 + mt;                                                     \
      f32x4 bb = *reinterpret_cast<const f32x4*>((bias) + gm * 16 + g * 4);    \
      _Pragma("unroll") for (int nt = 0; nt < 4; nt++) {                       \
        half4_t v;                                                             \
        _Pragma("unroll") for (int r = 0; r < 4; r++)                          \
            v[r] = (_Float16)fmaxf(acc[nt][r] + SF * bb[r], 0.0f);             \
        *reinterpret_cast<half4_t*>(                                           \
            &H[(nt * 16 + n16) * HPAD + gm * 16 + g * 4]) = v;                 \
      }                                                                        \
    }                                                                          \
    __syncthreads(); /* H writes visible to partner */                         \
  }

__global__ __launch_bounds__(256, 4) void fused_kernel(
    const float* __restrict__ coords, const _Float16* __restrict__ ph,
    const _Float16* __restrict__ w0h, const _Float16* __restrict__ w1h,
    const _Float16* __restrict__ w2h, const float* __restrict__ b0,
    const float* __restrict__ b1, const float* __restrict__ b2,
    const float* __restrict__ w3, const float* __restrict__ b3,
    float* __restrict__ out, int npts) {
  __shared__ alignas(16) _Float16 hbuf[2][64 * HPAD];  // 34816 B -> 4 blk/CU
  int tid = threadIdx.x;
  int sb = blockIdx.x;  // natural order: coalesced coords reads + out writes

  // ---- phase 1: sample 128 points; 2 threads/pt, 16 channels each ----
  {
    int ptl = tid >> 1, hf = tid & 1;  // waves 0,1 cover pair0; 2,3 pair1
    long pb = (long)sb * 128 + (ptl >> 6) * 64;
    if (pb + 64 > npts) pb = npts - 64;  // tail: duplicate identical work
    long pp = pb + (ptl & 63);
    float cx = coords[3 * pp + 0];
    float cy = coords[3 * pp + 1];
    float cz = coords[3 * pp + 2];
    float acc[16];
#pragma unroll
    for (int c = 0; c < 16; c++) acc[c] = 0.0f;
    samp16(ph, cx, cy, hf, acc);                  // plane 0: (x, y)
    samp16(ph + (1u << 23), cy, cz, hf, acc);     // plane 1: (y, z)
    samp16(ph + (2u << 23), cx, cz, hf, acc);     // plane 2: (x, z)
    half8 u0, u1;  // de-unioned converts (static indices -> registers)
#pragma unroll
    for (int c = 0; c < 8; c++) u0[c] = (_Float16)acc[c];
#pragma unroll
    for (int c = 0; c < 8; c++) u1[c] = (_Float16)acc[8 + c];
    _Float16* F = hbuf[ptl >> 6];
    // feats row stride FSTR=40 halves (80B: 16B-aligned, bank-uniform)
    st16(&F[(ptl & 63) * FSTR + hf * 16], u0);
    st16(&F[(ptl & 63) * FSTR + hf * 16 + 8], u1);
  }
  __syncthreads();  // feats visible to all waves

  // ---- phase 2: pair-split MLP ----
  int wv = tid >> 6, lane = tid & 63;
  int pair = wv >> 1, w = wv & 1;
  int n16 = lane & 15, g = lane >> 4;
  long base = (long)sb * 128 + pair * 64;
  if (base + 64 > npts) base = npts - 64;  // same clamp as phase 1
  _Float16* H = hbuf[pair];
  const f32x4 Z4 = {0.0f, 0.0f, 0.0f, 0.0f};

  // layer 0: C^T = W0(rows 64w..64w+63, x32) * feats^T(32x64); K=32.
  {
    half8 Bf[4];
#pragma unroll
    for (int nt = 0; nt < 4; nt++)
      Bf[nt] = ld16(&H[(nt * 16 + n16) * FSTR + g * 8]);  // LDS feats
    __syncthreads();  // feats reads done; epilogue may overwrite region
#pragma unroll
    for (int mt = 0; mt < 4; mt++) {
      half8 A = ld16(w0h + ((w * 4 + mt) * 16 + n16) * 32 + g * 8);
      f32x4 acc[4];
#pragma unroll
      for (int nt = 0; nt < 4; nt++)
        acc[nt] = __builtin_amdgcn_mfma_f32_16x16x32_f16(A, Bf[nt], Z4, 0, 0, 0);
      int gm = w * 4 + mt;
      f32x4 bb = *reinterpret_cast<const f32x4*>(b0 + gm * 16 + g * 4);
#pragma unroll
      for (int nt = 0; nt < 4; nt++) {
        half4_t v;
#pragma unroll
        for (int r = 0; r < 4; r++)
          v[r] = (_Float16)fmaxf(acc[nt][r] + SF * bb[r], 0.0f);
        *reinterpret_cast<half4_t*>(
            &H[(nt * 16 + n16) * HPAD + gm * 16 + g * 4]) = v;
      }
    }
    __syncthreads();  // H(L0) visible before L1 reads
  }

  LAYER_PAIR(w1h, b1)
  LAYER_PAIR(w2h, b2)

  // layer 3: out = dot(h2, w3)/S + b3, fp32 VALU.
  // Pair covers 64 pts; wave w takes pts w*32..+31. lane = pt' + 32*half;
  // each half does 8 of 16 chunks, reduce across halves via shfl_xor(32).
  int ptl3 = lane & 31, hh = lane >> 5;
  int pt = w * 32 + ptl3;
  float o = 0.0f;
#pragma unroll
  for (int ii = 0; ii < 8; ii++) {
    int i = hh * 8 + ii;
    half8 hv = ld16(&H[pt * HPAD + i * 8]);
#pragma unroll
    for (int j = 0; j < 8; j++) o += (float)hv[j] * w3[i * 8 + j];
  }
  o += __shfl_xor(o, 32);
  if (lane < 32) {
    out[base + pt] = o * (1.0f / SF) + b3[0];  // coalesced
  }
}

// ---------------- launch ----------------
extern "C" void kernel_launch(void* const* d_in, const int* in_sizes, int n_in,
                              void* d_out, int out_size, void* d_ws, size_t ws_size,
                              hipStream_t stream) {
  const float* coords = (const float*)d_in[0];
  const float* planes = (const float*)d_in[1];
  const float* w0 = (const float*)d_in[2];
  const float* b0 = (const float*)d_in[3];
  const float* w1 = (const float*)d_in[4];
  const float* b1 = (const float*)d_in[5];
  const float* w2 = (const float*)d_in[6];
  const float* b2 = (const float*)d_in[7];
  const float* w3 = (const float*)d_in[8];
  const float* b3 = (const float*)d_in[9];
  float* out = (float*)d_out;
  int npts = in_sizes[0] / 3;  // 1,000,000

  // workspace layout (bytes):
  //   ph       @ 0          50,331,648
  //   w0h      @ 50331648   8,192
  //   w1h      @ 50339840   32,768
  //   w2h      @ 50372608   32,768
  char* ws = (char*)d_ws;
  _Float16* ph = (_Float16*)ws;
  _Float16* w0h = (_Float16*)(ws + 50331648);
  _Float16* w1h = (_Float16*)(ws + 50339840);
  _Float16* w2h = (_Float16*)(ws + 50372608);

  int fblk = (npts + 127) / 128;  // 128 pts per block (2 pairs)

  // D1: transpose (3072) + weights (144) = 3216 blocks
  prep_kernel<<<3216, 256, 0, stream>>>(planes, ph, w0, w1, w2, w0h, w1h, w2h);
  // D2: fused sample + MLP, original point order
  fused_kernel<<<fblk, 256, 0, stream>>>(coords, ph, w0h, w1h, w2h, b0, b1, b2,
                                         w3, b3, out, npts);
}

// Round 11
// 414.072 us; speedup vs baseline: 1.8126x; 1.0022x over previous
//
#include <hip/hip_runtime.h>

// ---------------------------------------------------------------------------
// Triplane sample + 4-layer MLP, N=1e6 points. 2 dispatches:
//   D1 prep_kernel: [blocks 0..3071] transpose planes f32->f16 (x256, chan-
//       contiguous); [3072..3215] weights f32->f16.
//   D2 fused_kernel: sample 128 pts/block (original order) -> LDS feats ->
//       pair-split MFMA MLP -> out[p] (coalesced).
// Scale S=256 keeps f16 in normal range; epilogues add S*b in fp32; final
// layer divides by S in fp32.
//
// R1 (FAILED, 294us): 32-pt waves -> ILP collapse + 2x W traffic.
// R2 (NEUTRAL): pair-split 4 blk/CU; by-ref acc spilled (WRITE 70MB).
// R3 (NEUTRAL, 177us): de-spilled mlp; latency-chain bound.
// R4 (WIN, 598->509us): fused sample+MLP.
// R5/R6 (FAILED, ~800us): coop sort intrinsically stall-bound. Abandoned.
// R7 (WIN, 446us): dropped Morton sort; fused 287us, FETCH 577MB, occ 44%.
// R8 (FAILED, 750us): (128,5) reg cap -> catastrophic spill. Reverted.
// R9 (WIN, 415us): de-unioned hot paths -> WRITE 113->3.9MB, fused 253us.
// R10 (FAILED): fp8 planes absmax 4.3e-6 > threshold 1.9e-6 (R9 has only
//   4x headroom) -> texel quantization is off the table. Reverted to f16.
// R11: software-pipeline phase-1 gathers. R9's 3 dependent samp16 calls
//   serialized into >=3 exposed miss rounds (VGPR=64 proves it). Hoist all
//   12 corner addresses; issue plane0+plane1 loads (64 dest regs), blend
//   p0 while p1 in flight, issue plane2, blend p1, blend p2. Peak ~115
//   VGPR < 128 cap; exposure ~3 rounds -> ~1.3. Math identical to R9.
// ---------------------------------------------------------------------------

#define SF 256.0f
#define HPAD 136  // halves per point-row in LDS H (128 + 8 pad), 16B aligned
#define FSTR 40   // halves per point-row for LDS feats overlay (32 + 8 pad)

typedef _Float16 half8 __attribute__((ext_vector_type(8)));
typedef _Float16 half4_t __attribute__((ext_vector_type(4)));
typedef float f32x4 __attribute__((ext_vector_type(4)));

__device__ __attribute__((always_inline)) inline half8 ld16(const _Float16* p) {
  return *reinterpret_cast<const half8*>(p);
}
__device__ __attribute__((always_inline)) inline void st16(_Float16* p, half8 v) {
  *reinterpret_cast<half8*>(p) = v;
}

// ---------------- D1: prep (plane transpose + weights convert) -------------
__global__ __launch_bounds__(256) void prep_kernel(
    const float* __restrict__ planes, _Float16* __restrict__ ph,
    const float* __restrict__ w0, const float* __restrict__ w1,
    const float* __restrict__ w2, _Float16* __restrict__ w0h,
    _Float16* __restrict__ w1h, _Float16* __restrict__ w2h) {
  int bid = blockIdx.x;
  if (bid < 3072) {
    // plane transpose+convert+scale: 3*2^18 threads exactly
    int t = bid * 256 + threadIdx.x;
    int pid = t >> 18;
    int rem = t & ((1 << 18) - 1);              // y*512 + x
    const float* src = planes + ((size_t)pid << 23) + rem;  // [pid][c][y][x]
    half8 o[4];  // statically indexed after unroll -> registers
#pragma unroll
    for (int c = 0; c < 32; c++)
      o[c >> 3][c & 7] = (_Float16)(src[(size_t)c << 18] * SF);
    _Float16* dst = ph + ((size_t)t << 5);
#pragma unroll
    for (int i = 0; i < 4; i++) st16(dst + i * 8, o[i]);
  } else {
    // weights f32 -> f16: 36864 threads exactly (144 blocks)
    int t = (bid - 3072) * 256 + threadIdx.x;
    if (t < 4096) w0h[t] = (_Float16)w0[t];
    else if (t < 20480) w1h[t - 4096] = (_Float16)w1[t - 4096];
    else w2h[t - 20480] = (_Float16)w2[t - 20480];
  }
}

// ---------------- phase-1 sampling macros (software-pipelined) -------------
// SADDR: compute 4 corner pointers + 4 blend weights for plane sample S.
// SLOAD: issue the 8 16B loads for sample S into named half8 regs.
// SBLEND: fp32 blend of sample S into acc[16]. Math identical to R9.
#define SADDR(S, PL, X, Y)                                                     \
  float fx##S = ((X) + 1.0f) * 0.5f * 511.0f;                                  \
  float fy##S = ((Y) + 1.0f) * 0.5f * 511.0f;                                  \
  float x0f##S = floorf(fx##S), y0f##S = floorf(fy##S);                        \
  float wx1##S = fx##S - x0f##S, wy1##S = fy##S - y0f##S;                      \
  float wx0##S = 1.0f - wx1##S, wy0##S = 1.0f - wy1##S;                        \
  int x0##S = (int)x0f##S, y0##S = (int)y0f##S;                                \
  int x1##S = x0##S + 1, y1##S = y0##S + 1;                                    \
  float vx0##S = (x0##S >= 0 && x0##S < 512) ? 1.0f : 0.0f;                    \
  float vx1##S = (x1##S >= 0 && x1##S < 512) ? 1.0f : 0.0f;                    \
  float vy0##S = (y0##S >= 0 && y0##S < 512) ? 1.0f : 0.0f;                    \
  float vy1##S = (y1##S >= 0 && y1##S < 512) ? 1.0f : 0.0f;                    \
  int xc0##S = min(max(x0##S, 0), 511), xc1##S = min(max(x1##S, 0), 511);      \
  int yc0##S = min(max(y0##S, 0), 511), yc1##S = min(max(y1##S, 0), 511);      \
  float w00##S = wx0##S * wy0##S * vx0##S * vy0##S;                            \
  float w10##S = wx1##S * wy0##S * vx1##S * vy0##S;                            \
  float w01##S = wx0##S * wy1##S * vx0##S * vy1##S;                            \
  float w11##S = wx1##S * wy1##S * vx1##S * vy1##S;                            \
  const _Float16* p00##S = (PL) + ((((size_t)yc0##S << 9) + xc0##S) << 5);     \
  const _Float16* p10##S = (PL) + ((((size_t)yc0##S << 9) + xc1##S) << 5);     \
  const _Float16* p01##S = (PL) + ((((size_t)yc1##S << 9) + xc0##S) << 5);     \
  const _Float16* p11##S = (PL) + ((((size_t)yc1##S << 9) + xc1##S) << 5);

#define SLOAD(S)                                                               \
  half8 a0##S = ld16(p00##S), a1##S = ld16(p00##S + 8);                        \
  half8 b0##S = ld16(p10##S), b1##S = ld16(p10##S + 8);                        \
  half8 c0##S = ld16(p01##S), c1##S = ld16(p01##S + 8);                        \
  half8 d0##S = ld16(p11##S), d1##S = ld16(p11##S + 8);

#define SBLEND(S)                                                              \
  _Pragma("unroll") for (int j = 0; j < 8; j++) {                              \
    acc[j] += w00##S * (float)a0##S[j] + w10##S * (float)b0##S[j] +            \
              w01##S * (float)c0##S[j] + w11##S * (float)d0##S[j];             \
    acc[8 + j] += w00##S * (float)a1##S[j] + w10##S * (float)b1##S[j] +        \
                  w01##S * (float)c1##S[j] + w11##S * (float)d1##S[j];         \
  }

// ---------------- D2: fused sample + MLP ----------------
// Block = 256 threads = 2 pairs = 128 points; LDS 34816 B -> 4 blocks/CU.
// Phase 1: 2 threads/pt sample 16ch each, pipelined (p0+p1 loads in flight,
//   blend p0, issue p2, blend p1, blend p2) -> LDS feats (FSTR stride).
// Phase 2: pair-split MLP -- 2 waves share one 64-pt H buffer; wave w owns
//   hidden rows 64w..64w+63. MACRO body, per-mt fused epilogue: no spill.
#define LAYER_PAIR(Wg, bias)                                                   \
  {                                                                            \
    half8 Bf[4][4]; /* [nt][ks] : 64 regs */                                   \
    _Pragma("unroll") for (int nt = 0; nt < 4; nt++)                           \
    _Pragma("unroll") for (int ks = 0; ks < 4; ks++)                           \
        Bf[nt][ks] = ld16(&H[(nt * 16 + n16) * HPAD + ks * 32 + g * 8]);       \
    __syncthreads(); /* all H reads done; safe to overwrite */                 \
    _Pragma("unroll") for (int mt = 0; mt < 4; mt++) {                         \
      f32x4 acc[4];                                                            \
      _Pragma("unroll") for (int nt = 0; nt < 4; nt++) acc[nt] = Z4;           \
      _Pragma("unroll") for (int ks = 0; ks < 4; ks++) {                       \
        half8 A = ld16((Wg) + ((w * 4 + mt) * 16 + n16) * 128 + ks * 32 + g * 8); \
        _Pragma("unroll") for (int nt = 0; nt < 4; nt++)                       \
            acc[nt] = __builtin_amdgcn_mfma_f32_16x16x32_f16(A, Bf[nt][ks],    \
                                                             acc[nt], 0, 0, 0); \
      }                                                                        \
      int gm = w * 4 + mt;                                                     \
      f32x4 bb = *reinterpret_cast<const f32x4*>((bias) + gm * 16 + g * 4);    \
      _Pragma("unroll") for (int nt = 0; nt < 4; nt++) {                       \
        half4_t v;                                                             \
        _Pragma("unroll") for (int r = 0; r < 4; r++)                          \
            v[r] = (_Float16)fmaxf(acc[nt][r] + SF * bb[r], 0.0f);             \
        *reinterpret_cast<half4_t*>(                                           \
            &H[(nt * 16 + n16) * HPAD + gm * 16 + g * 4]) = v;                 \
      }                                                                        \
    }                                                                          \
    __syncthreads(); /* H writes visible to partner */                         \
  }

__global__ __launch_bounds__(256, 4) void fused_kernel(
    const float* __restrict__ coords, const _Float16* __restrict__ ph,
    const _Float16* __restrict__ w0h, const _Float16* __restrict__ w1h,
    const _Float16* __restrict__ w2h, const float* __restrict__ b0,
    const float* __restrict__ b1, const float* __restrict__ b2,
    const float* __restrict__ w3, const float* __restrict__ b3,
    float* __restrict__ out, int npts) {
  __shared__ alignas(16) _Float16 hbuf[2][64 * HPAD];  // 34816 B -> 4 blk/CU
  int tid = threadIdx.x;
  int sb = blockIdx.x;  // natural order: coalesced coords reads + out writes

  // ---- phase 1: sample 128 points; 2 threads/pt, 16 channels each ----
  {
    int ptl = tid >> 1, hf = tid & 1;  // waves 0,1 cover pair0; 2,3 pair1
    long pb = (long)sb * 128 + (ptl >> 6) * 64;
    if (pb + 64 > npts) pb = npts - 64;  // tail: duplicate identical work
    long pp = pb + (ptl & 63);
    float cx = coords[3 * pp + 0];
    float cy = coords[3 * pp + 1];
    float cz = coords[3 * pp + 2];
    const _Float16* PH = ph + hf * 16;  // fold channel-half into base
    // all 12 corner addresses first (pure VALU), then pipelined loads
    SADDR(0, PH, cx, cy)                    // plane 0: (x, y)
    SADDR(1, PH + (1u << 23), cy, cz)       // plane 1: (y, z)
    SADDR(2, PH + (2u << 23), cx, cz)       // plane 2: (x, z)
    float acc[16];
#pragma unroll
    for (int c = 0; c < 16; c++) acc[c] = 0.0f;
    SLOAD(0)   // 8 loads in flight
    SLOAD(1)   // 16 loads in flight (64 dest VGPRs)
    SBLEND(0)  // blend p0 while p1 outstanding
    SLOAD(2)   // issue p2 as p0's regs retire
    SBLEND(1)
    SBLEND(2)
    half8 u0, u1;  // static indices -> registers (no unions: R9 rule)
#pragma unroll
    for (int c = 0; c < 8; c++) u0[c] = (_Float16)acc[c];
#pragma unroll
    for (int c = 0; c < 8; c++) u1[c] = (_Float16)acc[8 + c];
    _Float16* F = hbuf[ptl >> 6];
    // feats row stride FSTR=40 halves (80B: 16B-aligned, bank-uniform)
    st16(&F[(ptl & 63) * FSTR + hf * 16], u0);
    st16(&F[(ptl & 63) * FSTR + hf * 16 + 8], u1);
  }
  __syncthreads();  // feats visible to all waves

  // ---- phase 2: pair-split MLP ----
  int wv = tid >> 6, lane = tid & 63;
  int pair = wv >> 1, w = wv & 1;
  int n16 = lane & 15, g = lane >> 4;
  long base = (long)sb * 128 + pair * 64;
  if (base + 64 > npts) base = npts - 64;  // same clamp as phase 1
  _Float16* H = hbuf[pair];
  const f32x4 Z4 = {0.0f, 0.0f, 0.0f, 0.0f};

  // layer 0: C^T = W0(rows 64w..64w+63, x32) * feats^T(32x64); K=32.
  {
    half8 Bf[4];
#pragma unroll
    for (int nt = 0; nt < 4; nt++)
      Bf[nt] = ld16(&H[(nt * 16 + n16) * FSTR + g * 8]);  // LDS feats
    __syncthreads();  // feats reads done; epilogue may overwrite region
#pragma unroll
    for (int mt = 0; mt < 4; mt++) {
      half8 A = ld16(w0h + ((w * 4 + mt) * 16 + n16) * 32 + g * 8);
      f32x4 acc[4];
#pragma unroll
      for (int nt = 0; nt < 4; nt++)
        acc[nt] = __builtin_amdgcn_mfma_f32_16x16x32_f16(A, Bf[nt], Z4, 0, 0, 0);
      int gm = w * 4 + mt;
      f32x4 bb = *reinterpret_cast<const f32x4*>(b0 + gm * 16 + g * 4);
#pragma unroll
      for (int nt = 0; nt < 4; nt++) {
        half4_t v;
#pragma unroll
        for (int r = 0; r < 4; r++)
          v[r] = (_Float16)fmaxf(acc[nt][r] + SF * bb[r], 0.0f);
        *reinterpret_cast<half4_t*>(
            &H[(nt * 16 + n16) * HPAD + gm * 16 + g * 4]) = v;
      }
    }
    __syncthreads();  // H(L0) visible before L1 reads
  }

  LAYER_PAIR(w1h, b1)
  LAYER_PAIR(w2h, b2)

  // layer 3: out = dot(h2, w3)/S + b3, fp32 VALU.
  // Pair covers 64 pts; wave w takes pts w*32..+31. lane = pt' + 32*half;
  // each half does 8 of 16 chunks, reduce across halves via shfl_xor(32).
  int ptl3 = lane & 31, hh = lane >> 5;
  int pt = w * 32 + ptl3;
  float o = 0.0f;
#pragma unroll
  for (int ii = 0; ii < 8; ii++) {
    int i = hh * 8 + ii;
    half8 hv = ld16(&H[pt * HPAD + i * 8]);
#pragma unroll
    for (int j = 0; j < 8; j++) o += (float)hv[j] * w3[i * 8 + j];
  }
  o += __shfl_xor(o, 32);
  if (lane < 32) {
    out[base + pt] = o * (1.0f / SF) + b3[0];  // coalesced
  }
}

// ---------------- launch ----------------
extern "C" void kernel_launch(void* const* d_in, const int* in_sizes, int n_in,
                              void* d_out, int out_size, void* d_ws, size_t ws_size,
                              hipStream_t stream) {
  const float* coords = (const float*)d_in[0];
  const float* planes = (const float*)d_in[1];
  const float* w0 = (const float*)d_in[2];
  const float* b0 = (const float*)d_in[3];
  const float* w1 = (const float*)d_in[4];
  const float* b1 = (const float*)d_in[5];
  const float* w2 = (const float*)d_in[6];
  const float* b2 = (const float*)d_in[7];
  const float* w3 = (const float*)d_in[8];
  const float* b3 = (const float*)d_in[9];
  float* out = (float*)d_out;
  int npts = in_sizes[0] / 3;  // 1,000,000

  // workspace layout (bytes):
  //   ph       @ 0          50,331,648
  //   w0h      @ 50331648   8,192
  //   w1h      @ 50339840   32,768
  //   w2h      @ 50372608   32,768
  char* ws = (char*)d_ws;
  _Float16* ph = (_Float16*)ws;
  _Float16* w0h = (_Float16*)(ws + 50331648);
  _Float16* w1h = (_Float16*)(ws + 50339840);
  _Float16* w2h = (_Float16*)(ws + 50372608);

  int fblk = (npts + 127) / 128;  // 128 pts per block (2 pairs)

  // D1: transpose (3072) + weights (144) = 3216 blocks
  prep_kernel<<<3216, 256, 0, stream>>>(planes, ph, w0, w1, w2, w0h, w1h, w2h);
  // D2: fused sample + MLP, original point order
  fused_kernel<<<fblk, 256, 0, stream>>>(coords, ph, w0h, w1h, w2h, b0, b1, b2,
                                         w3, b3, out, npts);
}